// Round 11
// baseline (272.931 us; speedup 1.0000x reference)
//
#include <hip/hip_runtime.h>
#include <hip/hip_bf16.h>

// Problem constants
#define B_ROWS 16384
#define OBS_D  512
#define H_D    1024
#define N_AG   9

typedef __attribute__((ext_vector_type(8))) short short8;
typedef __attribute__((ext_vector_type(4))) float floatx4;

__device__ __forceinline__ unsigned short f_to_bf_raw(float f) {
  union { float f; unsigned u; } c; c.f = f;
  unsigned u = c.u;
  u = u + 0x7FFF + ((u >> 16) & 1);   // round-to-nearest-even
  return (unsigned short)(u >> 16);
}

// Fragment-major WEIGHT layout (B operand only; A stays row-major):
//   frag_tile = (n>>4)*KT32 + (k>>5)
//   lane      = (n&15) | (((k>>3)&3)<<4)
//   j         = k&7
// offset (bf16 units) = (frag_tile*64 + lane)*8 + j
// -> a wave's B-frag load is base + lane*16: one coalesced 1KB dwordx4 line.
__device__ __forceinline__ size_t frag_off(int n, int k, int KT32) {
  const int ft = (n >> 4) * KT32 + (k >> 5);
  const int ln = (n & 15) | (((k >> 3) & 3) << 4);
  return ((size_t)ft * 64 + ln) * 8 + (k & 7);
}

// ---------------------------------------------------------------------------
// Mega-prep: obs cast row-major, W1f/W2f/WHf frag-major
// (WH = [Wc1|Wt1|Wk1fold]), bias2048/w2cat concat. Branch block-uniform.
// Grid: [0,4096) obs | [4096,4608) W1f | [4608,5632) W2f |
//       [5632,7680) WHf | [7680,7688) vecs
// ---------------------------------------------------------------------------
__global__ __launch_bounds__(256) void prep_all(
    const float* __restrict__ obs,
    const float* __restrict__ W1, const float* __restrict__ W2,
    const float* __restrict__ Wc1, const float* __restrict__ Wt1,
    const float* __restrict__ Wk1,
    const float* __restrict__ bc1, const float* __restrict__ bt1,
    const float* __restrict__ bk1,
    const float* __restrict__ Wc2, const float* __restrict__ Wt2,
    const float* __restrict__ Wk2,
    unsigned short* __restrict__ obs_bf,
    unsigned short* __restrict__ W1f, unsigned short* __restrict__ W2f,
    unsigned short* __restrict__ WHf,
    float* __restrict__ bias2048, float* __restrict__ w2cat) {
  __shared__ float t[32][33];
  const int bx  = blockIdx.x;
  const int tid = threadIdx.x;

  if (bx < 4096) {                       // obs fp32 -> bf16, 8 elems/thread
    int i = (bx * 256 + tid) * 8;
    float4 a = *(const float4*)(obs + i);
    float4 b = *(const float4*)(obs + i + 4);
    short8 o;
    o[0] = (short)f_to_bf_raw(a.x); o[1] = (short)f_to_bf_raw(a.y);
    o[2] = (short)f_to_bf_raw(a.z); o[3] = (short)f_to_bf_raw(a.w);
    o[4] = (short)f_to_bf_raw(b.x); o[5] = (short)f_to_bf_raw(b.y);
    o[6] = (short)f_to_bf_raw(b.z); o[7] = (short)f_to_bf_raw(b.w);
    *(short8*)(obs_bf + i) = o;
    return;
  }

  const int tx = tid & 31;
  const int ty = tid >> 5;   // 0..7

  if (bx < 4608) {                       // W1 [512,1024] -> W1f (K=512,KT32=16)
    const int tt = bx - 4096;
    const int k0 = (tt & 15) * 32;
    const int n0 = (tt >> 4) * 32;
#pragma unroll
    for (int i = ty; i < 32; i += 8)
      t[i][tx] = W1[(size_t)(k0 + i) * 1024 + n0 + tx];
    __syncthreads();
#pragma unroll
    for (int i = ty; i < 32; i += 8)
      W1f[frag_off(n0 + i, k0 + tx, 16)] = f_to_bf_raw(t[tx][i]);
    return;
  }

  if (bx < 5632) {                       // W2 [1024,1024] -> W2f (KT32=32)
    const int tt = bx - 4608;
    const int k0 = (tt & 31) * 32;
    const int n0 = (tt >> 5) * 32;
#pragma unroll
    for (int i = ty; i < 32; i += 8)
      t[i][tx] = W2[(size_t)(k0 + i) * 1024 + n0 + tx];
    __syncthreads();
#pragma unroll
    for (int i = ty; i < 32; i += 8)
      W2f[frag_off(n0 + i, k0 + tx, 32)] = f_to_bf_raw(t[tx][i]);
    return;
  }

  if (bx < 7680) {                       // WHf [2048 n,1024 k] (KT32=32)
    const int tt = bx - 5632;
    const int k0 = (tt & 31) * 32;
    const int n0 = (tt >> 5) * 32;       // region-uniform per block
#pragma unroll
    for (int i = ty; i < 32; i += 8) {
      const int n = n0 + tx;
      float v;
      if (n0 < 512)
        v = Wc1[(size_t)(k0 + i) * 512 + n];
      else if (n0 < 1024)
        v = Wt1[(size_t)(k0 + i) * 512 + (n - 512)];
      else
        v = Wk1[(size_t)(k0 + i) * 1024 + (n - 1024)]
          + Wk1[(size_t)(k0 + i + 1024) * 1024 + (n - 1024)];
      t[i][tx] = v;
    }
    __syncthreads();
#pragma unroll
    for (int i = ty; i < 32; i += 8)
      WHf[frag_off(n0 + i, k0 + tx, 32)] = f_to_bf_raw(t[tx][i]);
    return;
  }

  {                                      // bias2048 / w2cat
    int n = (bx - 7680) * 256 + tid;
    float b, w;
    if (n < 512)       { b = bc1[n];        w = Wc2[n]; }
    else if (n < 1024) { b = bt1[n - 512];  w = Wt2[n - 512]; }
    else               { b = bk1[n - 1024]; w = Wk2[n - 1024]; }
    bias2048[n] = b;
    w2cat[n] = w;
  }
}

// ===========================================================================
// GEMM core v10: 128x128 tile, BK=64, ONE barrier per iter, tuned for
// 4 blocks/CU co-residency (round-10 was latency-bound at 3 blocks/CU,
// doubly capped by 48KB LDS and 136 unified regs):
//  - A: LDS DOUBLE-buffer (2 x 16 KB = 32 KB), DMA dist-1 (issued right
//    after sync k, drained at sync k+1 -> one full 32-MFMA compute phase
//    in flight). Same 128B-row swizzle as v9 (chunk c of row r at c^(r&7),
//    global-side permute; measured 0 conflicts).
//  - B: frag-major global (L2-hot), coalesced 1KB dwordx4 frag loads,
//    loaded JIT per k-half (NO register dbuf: saves 32-64 VGPRs; the JIT
//    latency is covered by the extra co-resident waves).
//  - Per-iter: Fb0/Fa0 loads -> 16 MFMA -> Fb1/Fa1 loads -> 16 MFMA.
//    Transient reg peak ~= acc(64) + frags(32) + addr -> fits 128/wave,
//    enforced by __launch_bounds__(256,4) (4 waves/EU = 4 blocks/CU).
// K template constant -> full unroll -> all indices compile-time (r6 lesson).
// r9 lesson: A must be LDS-shared between waves.
// ===========================================================================
#define GLD_LDS(gp, lp)                                                        \
  __builtin_amdgcn_global_load_lds(                                            \
      (const __attribute__((address_space(1))) void*)(gp),                     \
      (__attribute__((address_space(3))) void*)(lp), 16, 0, 0)

#define GEMM_CORE_V10(ACC_DECL)                                                \
  __shared__ __align__(16) unsigned short As[2][128 * 64];  /* 32 KB */        \
  const int tid  = threadIdx.x;                                                \
  const int lane = tid & 63;                                                   \
  const int wave = tid >> 6;                                                   \
  const int m0 = blockIdx.x * 128;                                             \
  const int n0 = blockIdx.y * 128;                                             \
  const int wm = (wave & 1) * 64;                                              \
  const int wn = (wave >> 1) * 64;                                             \
  const int fr = lane & 15;                                                    \
  const int fq = lane >> 4;                                                    \
  ACC_DECL;                                                                    \
  constexpr int KT   = K >> 6;     /* BK=64 iterations      */                 \
  constexpr int KT32 = K >> 5;     /* 32-wide k-tiles (B)   */                 \
  const size_t rowb = (size_t)K * 2;                                           \
  const int srow8  = lane >> 3;                 /* 0..7 row in 8-row group */  \
  const int schunk = (lane & 7) ^ srow8;        /* swizzled global chunk   */  \
  const char* gA = (const char*)A + (size_t)(m0 + wave * 32 + srow8) * rowb    \
                   + schunk * 16;                                              \
  char* lAw = (char*)&As[0][0] + wave * 4096 + lane * 16;                      \
  const unsigned short* gB =                                                   \
      Bf + ((size_t)(((n0 + wn) >> 4) * KT32) * 64 + lane) * 8;                \
  const int fsA = (wm + fr) * 128;                                             \
  const int sl0 = ((fq)     ^ (fr & 7)) * 16;                                  \
  const int sl1 = ((4 + fq) ^ (fr & 7)) * 16;                                  \
  /* prologue: DMA tile 0 -> buf 0 */                                          \
  _Pragma("unroll")                                                            \
  for (int j = 0; j < 4; ++j)                                                  \
    GLD_LDS(gA + (size_t)j * 8 * rowb, lAw + j * 1024);                        \
  _Pragma("unroll")                                                            \
  for (int k = 0; k < KT; ++k) {       /* constexpr bound -> full unroll */    \
    __syncthreads();   /* drains DMA(k) (one full iter in flight for k>0) */   \
    if (k + 1 < KT) {                                                          \
      char* d = (char*)&As[(k + 1) & 1][0] + wave * 4096 + lane * 16;          \
      const char* g = gA + (size_t)(k + 1) * 128;                              \
      _Pragma("unroll")                                                        \
      for (int j = 0; j < 4; ++j)                                              \
        GLD_LDS(g + (size_t)j * 8 * rowb, d + j * 1024);                       \
    }                                                                          \
    const char* bA = (const char*)&As[k & 1][0];                               \
    {                                                                          \
      short8 Fb0[4], Fa0[4];                                                   \
      _Pragma("unroll")                                                        \
      for (int ni = 0; ni < 4; ++ni)                                           \
        Fb0[ni] = *(const short8*)(gB + ((size_t)ni * KT32 + 2 * k) * 512);    \
      _Pragma("unroll")                                                        \
      for (int mi = 0; mi < 4; ++mi)                                           \
        Fa0[mi] = *(const short8*)(bA + fsA + mi * 2048 + sl0);                \
      _Pragma("unroll")                                                        \
      for (int mi = 0; mi < 4; ++mi)                                           \
        _Pragma("unroll")                                                      \
        for (int ni = 0; ni < 4; ++ni)                                         \
          acc[mi][ni] = __builtin_amdgcn_mfma_f32_16x16x32_bf16(               \
              Fa0[mi], Fb0[ni], acc[mi][ni], 0, 0, 0);                         \
    }                                                                          \
    {                                                                          \
      short8 Fb1[4], Fa1[4];                                                   \
      _Pragma("unroll")                                                        \
      for (int ni = 0; ni < 4; ++ni)                                           \
        Fb1[ni] = *(const short8*)(gB + ((size_t)ni * KT32 + 2 * k + 1) * 512);\
      _Pragma("unroll")                                                        \
      for (int mi = 0; mi < 4; ++mi)                                           \
        Fa1[mi] = *(const short8*)(bA + fsA + mi * 2048 + sl1);                \
      _Pragma("unroll")                                                        \
      for (int mi = 0; mi < 4; ++mi)                                           \
        _Pragma("unroll")                                                      \
        for (int ni = 0; ni < 4; ++ni)                                         \
          acc[mi][ni] = __builtin_amdgcn_mfma_f32_16x16x32_bf16(               \
              Fa1[mi], Fb1[ni], acc[mi][ni], 0, 0, 0);                         \
    }                                                                          \
  }

#define ACC_INIT                                                               \
  floatx4 acc[4][4];                                                           \
  _Pragma("unroll")                                                            \
  for (int i = 0; i < 4; ++i)                                                  \
    _Pragma("unroll")                                                          \
    for (int j = 0; j < 4; ++j) acc[i][j] = (floatx4){0.f, 0.f, 0.f, 0.f}

// ---------------------------------------------------------------------------
// GEMM: C = relu(A @ B^T + bias), bf16 out (row-major). Bf frag-major.
// ---------------------------------------------------------------------------
template <int K>
__global__ __launch_bounds__(256, 4) void gemm_bias_relu(
    const unsigned short* __restrict__ A,
    const unsigned short* __restrict__ Bf,
    const float* __restrict__ bias,
    unsigned short* __restrict__ C,
    int M, int N) {
  GEMM_CORE_V10(ACC_INIT)

  // Epilogue: C/D layout col=lane&15, row=(lane>>4)*4+reg
#pragma unroll
  for (int ni = 0; ni < 4; ++ni) {
    const int gn = n0 + wn + ni * 16 + fr;
    const float bv = bias[gn];
#pragma unroll
    for (int mi = 0; mi < 4; ++mi) {
#pragma unroll
      for (int r = 0; r < 4; ++r) {
        const int gm = m0 + wm + mi * 16 + fq * 4 + r;
        float v = acc[mi][ni][r] + bv;
        v = v > 0.f ? v : 0.f;
        C[(size_t)gm * N + gn] = f_to_bf_raw(v);
      }
    }
  }
}

// ---------------------------------------------------------------------------
// Fused heads GEMM: relu(G @ WH^T + bias2048) dotted with w2cat in-register,
// non-atomic partials part[j][row], j = blockIdx.y*2 + wave_half in [0,32).
// j 0..7 coverage, 8..15 tracking, 16..31 cooperation.
// ---------------------------------------------------------------------------
template <int K>
__global__ __launch_bounds__(256, 4) void gemm_heads_fused(
    const unsigned short* __restrict__ A,    // G row-major [B,1024]
    const unsigned short* __restrict__ Bf,   // WHf frag-major [2048,1024]
    const float* __restrict__ bias,          // bias2048
    const float* __restrict__ w2,            // w2cat
    float* __restrict__ part,                // [32][B_ROWS]
    int M, int N) {
  GEMM_CORE_V10(ACC_INIT)

  const int j = blockIdx.y * 2 + (wave >> 1);
  float w2v[4], bv[4];
#pragma unroll
  for (int ni = 0; ni < 4; ++ni) {
    const int gn = n0 + wn + ni * 16 + fr;
    w2v[ni] = w2[gn];
    bv[ni]  = bias[gn];
  }
#pragma unroll
  for (int mi = 0; mi < 4; ++mi) {
#pragma unroll
    for (int r = 0; r < 4; ++r) {
      float p = 0.f;
#pragma unroll
      for (int ni = 0; ni < 4; ++ni) {
        float v = acc[mi][ni][r] + bv[ni];
        v = v > 0.f ? v : 0.f;
        p += v * w2v[ni];
      }
      p += __shfl_xor(p, 1);
      p += __shfl_xor(p, 2);
      p += __shfl_xor(p, 4);
      p += __shfl_xor(p, 8);
      if (fr == 0) {
        const int gm = m0 + wm + mi * 16 + fq * 4 + r;
        part[(size_t)j * B_ROWS + gm] = p;
      }
    }
  }
}

// ---------------------------------------------------------------------------
// Final: sum partials, sigmoid, broadcast to out [3, B, 9]. 1 thread/row.
// ---------------------------------------------------------------------------
__global__ __launch_bounds__(256) void final_out(
    const float* __restrict__ part,
    const float* __restrict__ bc2, const float* __restrict__ bt2,
    const float* __restrict__ bk2, float* __restrict__ out) {
  const int row = blockIdx.x * 256 + threadIdx.x;
  float sc = 0.f, st = 0.f, sk = 0.f;
#pragma unroll
  for (int j = 0; j < 8; ++j)  sc += part[(size_t)j * B_ROWS + row];
#pragma unroll
  for (int j = 8; j < 16; ++j) st += part[(size_t)j * B_ROWS + row];
#pragma unroll
  for (int j = 16; j < 32; ++j) sk += part[(size_t)j * B_ROWS + row];
  const float cv = 1.f / (1.f + expf(-(sc + bc2[0])));
  const float tv = 1.f / (1.f + expf(-(st + bt2[0])));
  const float kv = 1.f / (1.f + expf(-(sk + bk2[0])));
  float* o0 = out + (size_t)row * N_AG;
  float* o1 = out + (size_t)(B_ROWS + row) * N_AG;
  float* o2 = out + (size_t)(2 * B_ROWS + row) * N_AG;
#pragma unroll
  for (int a = 0; a < N_AG; ++a) { o0[a] = cv; o1[a] = tv; o2[a] = kv; }
}

// ---------------------------------------------------------------------------
extern "C" void kernel_launch(void* const* d_in, const int* in_sizes, int n_in,
                              void* d_out, int out_size, void* d_ws, size_t ws_size,
                              hipStream_t stream) {
  const float* obs = (const float*)d_in[0];
  // d_in[1] agent_positions: unused (outputs don't depend on it)
  const float* W1  = (const float*)d_in[2];
  const float* b1  = (const float*)d_in[3];
  const float* W2  = (const float*)d_in[4];
  const float* b2  = (const float*)d_in[5];
  const float* Wc1 = (const float*)d_in[6];
  const float* bc1 = (const float*)d_in[7];
  const float* Wc2 = (const float*)d_in[8];
  const float* bc2 = (const float*)d_in[9];
  const float* Wt1 = (const float*)d_in[10];
  const float* bt1 = (const float*)d_in[11];
  const float* Wt2 = (const float*)d_in[12];
  const float* bt2 = (const float*)d_in[13];
  const float* Wk1 = (const float*)d_in[14];
  const float* bk1 = (const float*)d_in[15];
  const float* Wk2 = (const float*)d_in[16];
  const float* bk2 = (const float*)d_in[17];
  float* out = (float*)d_out;

  // Workspace layout. PART aliases obs_bf (disjoint lifetimes).
  char* ws = (char*)d_ws;
  unsigned short* obs_bf  = (unsigned short*)(ws + 0);         // 16 MB
  float*          PART    = (float*)(ws + 0);                  // 2 MB (alias)
  unsigned short* W1f     = (unsigned short*)(ws + 16777216);  // 1 MB  frag-major
  unsigned short* W2f     = (unsigned short*)(ws + 17825792);  // 2 MB  frag-major
  unsigned short* WHf     = (unsigned short*)(ws + 19922944);  // 4 MB  frag-major
  float*          bias2048= (float*)(ws + 24117248);           // 8 KB
  float*          w2cat   = (float*)(ws + 24125440);           // 8 KB
  unsigned short* G1      = (unsigned short*)(ws + 24330240);  // 32 MB
  unsigned short* G       = (unsigned short*)(ws + 57884672);  // 32 MB

  prep_all<<<7688, 256, 0, stream>>>(obs, W1, W2, Wc1, Wt1, Wk1,
                                     bc1, bt1, bk1, Wc2, Wt2, Wk2,
                                     obs_bf, W1f, W2f, WHf, bias2048, w2cat);

  gemm_bias_relu<512><<<dim3(128, 8), 256, 0, stream>>>(obs_bf, W1f, b1, G1, B_ROWS, 1024);
  gemm_bias_relu<1024><<<dim3(128, 8), 256, 0, stream>>>(G1, W2f, b2, G, B_ROWS, 1024);

  gemm_heads_fused<1024><<<dim3(128, 16), 256, 0, stream>>>(G, WHf, bias2048, w2cat, PART,
                                                            B_ROWS, 2048);

  final_out<<<B_ROWS / 256, 256, 0, stream>>>(PART, bc2, bt2, bk2, out);
}

// Round 12
// 258.421 us; speedup vs baseline: 1.0561x; 1.0561x over previous
//
#include <hip/hip_runtime.h>
#include <hip/hip_bf16.h>

// Problem constants
#define B_ROWS 16384
#define OBS_D  512
#define H_D    1024
#define N_AG   9

typedef __attribute__((ext_vector_type(8))) short short8;
typedef __attribute__((ext_vector_type(4))) float floatx4;

__device__ __forceinline__ unsigned short f_to_bf_raw(float f) {
  union { float f; unsigned u; } c; c.f = f;
  unsigned u = c.u;
  u = u + 0x7FFF + ((u >> 16) & 1);   // round-to-nearest-even
  return (unsigned short)(u >> 16);
}

// Fragment-major WEIGHT layout, K-MAJOR within 64-col groups (round-12):
//   group     = n>>6
//   frag_tile = (group*KT32 + (k>>5))*4 + ((n>>4)&3)
//   lane      = (n&15) | (((k>>3)&3)<<4)      (MFMA 16x16x32 B-operand)
//   j         = k&7
// offset (bf16 units) = (frag_tile*64 + lane)*8 + j
// -> in the kernel, a wave's 4 ni-frags for one k-step sit at ONE base +
//    {0,1024,2048,3072} bytes (13-bit imm range!) + lane*16, and the k-step
//    advance is a single pointer += 4096 B. B addressing = 2 VGPRs total
//    (round-11's 8 per-ni address VGPRs were what pushed us into spill).
__device__ __forceinline__ size_t frag_off64(int n, int k, int KT32) {
  const int ft = ((n >> 6) * KT32 + (k >> 5)) * 4 + ((n >> 4) & 3);
  const int ln = (n & 15) | (((k >> 3) & 3) << 4);
  return ((size_t)ft * 64 + ln) * 8 + (k & 7);
}

// ---------------------------------------------------------------------------
// Mega-prep: obs cast row-major, W1f/W2f/WHf frag-major(k-major-in-group)
// (WH = [Wc1|Wt1|Wk1fold]), bias2048/w2cat concat. Branch block-uniform.
// Grid: [0,4096) obs | [4096,4608) W1f | [4608,5632) W2f |
//       [5632,7680) WHf | [7680,7688) vecs
// ---------------------------------------------------------------------------
__global__ __launch_bounds__(256) void prep_all(
    const float* __restrict__ obs,
    const float* __restrict__ W1, const float* __restrict__ W2,
    const float* __restrict__ Wc1, const float* __restrict__ Wt1,
    const float* __restrict__ Wk1,
    const float* __restrict__ bc1, const float* __restrict__ bt1,
    const float* __restrict__ bk1,
    const float* __restrict__ Wc2, const float* __restrict__ Wt2,
    const float* __restrict__ Wk2,
    unsigned short* __restrict__ obs_bf,
    unsigned short* __restrict__ W1f, unsigned short* __restrict__ W2f,
    unsigned short* __restrict__ WHf,
    float* __restrict__ bias2048, float* __restrict__ w2cat) {
  __shared__ float t[32][33];
  const int bx  = blockIdx.x;
  const int tid = threadIdx.x;

  if (bx < 4096) {                       // obs fp32 -> bf16, 8 elems/thread
    int i = (bx * 256 + tid) * 8;
    float4 a = *(const float4*)(obs + i);
    float4 b = *(const float4*)(obs + i + 4);
    short8 o;
    o[0] = (short)f_to_bf_raw(a.x); o[1] = (short)f_to_bf_raw(a.y);
    o[2] = (short)f_to_bf_raw(a.z); o[3] = (short)f_to_bf_raw(a.w);
    o[4] = (short)f_to_bf_raw(b.x); o[5] = (short)f_to_bf_raw(b.y);
    o[6] = (short)f_to_bf_raw(b.z); o[7] = (short)f_to_bf_raw(b.w);
    *(short8*)(obs_bf + i) = o;
    return;
  }

  const int tx = tid & 31;
  const int ty = tid >> 5;   // 0..7

  if (bx < 4608) {                       // W1 [512,1024] -> W1f (K=512,KT32=16)
    const int tt = bx - 4096;
    const int k0 = (tt & 15) * 32;
    const int n0 = (tt >> 4) * 32;
#pragma unroll
    for (int i = ty; i < 32; i += 8)
      t[i][tx] = W1[(size_t)(k0 + i) * 1024 + n0 + tx];
    __syncthreads();
#pragma unroll
    for (int i = ty; i < 32; i += 8)
      W1f[frag_off64(n0 + i, k0 + tx, 16)] = f_to_bf_raw(t[tx][i]);
    return;
  }

  if (bx < 5632) {                       // W2 [1024,1024] -> W2f (KT32=32)
    const int tt = bx - 4608;
    const int k0 = (tt & 31) * 32;
    const int n0 = (tt >> 5) * 32;
#pragma unroll
    for (int i = ty; i < 32; i += 8)
      t[i][tx] = W2[(size_t)(k0 + i) * 1024 + n0 + tx];
    __syncthreads();
#pragma unroll
    for (int i = ty; i < 32; i += 8)
      W2f[frag_off64(n0 + i, k0 + tx, 32)] = f_to_bf_raw(t[tx][i]);
    return;
  }

  if (bx < 7680) {                       // WHf [2048 n,1024 k] (KT32=32)
    const int tt = bx - 5632;
    const int k0 = (tt & 31) * 32;
    const int n0 = (tt >> 5) * 32;       // region-uniform per block
#pragma unroll
    for (int i = ty; i < 32; i += 8) {
      const int n = n0 + tx;
      float v;
      if (n0 < 512)
        v = Wc1[(size_t)(k0 + i) * 512 + n];
      else if (n0 < 1024)
        v = Wt1[(size_t)(k0 + i) * 512 + (n - 512)];
      else
        v = Wk1[(size_t)(k0 + i) * 1024 + (n - 1024)]
          + Wk1[(size_t)(k0 + i + 1024) * 1024 + (n - 1024)];
      t[i][tx] = v;
    }
    __syncthreads();
#pragma unroll
    for (int i = ty; i < 32; i += 8)
      WHf[frag_off64(n0 + i, k0 + tx, 32)] = f_to_bf_raw(t[tx][i]);
    return;
  }

  {                                      // bias2048 / w2cat
    int n = (bx - 7680) * 256 + tid;
    float b, w;
    if (n < 512)       { b = bc1[n];        w = Wc2[n]; }
    else if (n < 1024) { b = bt1[n - 512];  w = Wt2[n - 512]; }
    else               { b = bk1[n - 1024]; w = Wk2[n - 1024]; }
    bias2048[n] = b;
    w2cat[n] = w;
  }
}

// ===========================================================================
// GEMM core v11: 128x128 tile, BK=64, ONE barrier per iter, 4 blocks/CU:
//  - A: LDS DOUBLE-buffer (2 x 16 KB = 32 KB), DMA dist-1 (issued after
//    sync k, drained at sync k+1 -> a full 32-MFMA compute phase in flight).
//    128B-row swizzle: chunk c of row r at c^(r&7), global-side permute
//    (measured 0 conflicts, rounds 10/11).
//  - B: frag-major k-major-in-64group global (L2-hot), JIT per k-half:
//    4 ni-frag loads = ONE rolling base + imm {0,1K,2K,3K} + lane*16,
//    base += 4096B per half. ~2 VGPRs of B addressing (vs 8 in r11 -> spill).
//  - Reg budget: acc 64 AGPR + ~50 VGPR working set fits 128 =
//    __launch_bounds__(256,4) WITHOUT spill (r11 tripwire: WRITE_SIZE).
//    4 blocks/CU makes heads grid (2048) exactly 2 rounds, gemm2 (1024)
//    exactly 1 round -> no occupancy-quantization tail.
// K template constant -> full unroll -> all indices compile-time (r6 lesson).
// r9 lesson: A must be LDS-shared between waves.
// ===========================================================================
#define GLD_LDS(gp, lp)                                                        \
  __builtin_amdgcn_global_load_lds(                                            \
      (const __attribute__((address_space(1))) void*)(gp),                     \
      (__attribute__((address_space(3))) void*)(lp), 16, 0, 0)

#define GEMM_CORE_V11(ACC_DECL)                                                \
  __shared__ __align__(16) unsigned short As[2][128 * 64];  /* 32 KB */        \
  const int tid  = threadIdx.x;                                                \
  const int lane = tid & 63;                                                   \
  const int wave = tid >> 6;                                                   \
  const int m0 = blockIdx.x * 128;                                             \
  const int n0 = blockIdx.y * 128;                                             \
  const int wm = (wave & 1) * 64;                                              \
  const int wn = (wave >> 1) * 64;                                             \
  const int fr = lane & 15;                                                    \
  const int fq = lane >> 4;                                                    \
  ACC_DECL;                                                                    \
  constexpr int KT   = K >> 6;     /* BK=64 iterations      */                 \
  constexpr int KT32 = K >> 5;     /* 32-wide k-tiles (B)   */                 \
  const size_t rowb = (size_t)K * 2;                                           \
  const int srow8  = lane >> 3;                 /* 0..7 row in 8-row group */  \
  const int schunk = (lane & 7) ^ srow8;        /* swizzled global chunk   */  \
  const char* gA = (const char*)A + (size_t)(m0 + wave * 32 + srow8) * rowb    \
                   + schunk * 16;                                              \
  char* lAw = (char*)&As[0][0] + wave * 4096 + lane * 16;                      \
  /* rolling B pointer: group base + lane*16; advances 4096B per k-half */     \
  const char* gBk = (const char*)Bf                                            \
      + ((size_t)(((n0 + wn) >> 6) * KT32) * 4) * 1024 + lane * 16;            \
  const int fsA = (wm + fr) * 128;                                             \
  const int sl0 = ((fq)     ^ (fr & 7)) * 16;                                  \
  const int sl1 = ((4 + fq) ^ (fr & 7)) * 16;                                  \
  /* prologue: DMA tile 0 -> buf 0 */                                          \
  _Pragma("unroll")                                                            \
  for (int j = 0; j < 4; ++j)                                                  \
    GLD_LDS(gA + (size_t)j * 8 * rowb, lAw + j * 1024);                        \
  _Pragma("unroll")                                                            \
  for (int k = 0; k < KT; ++k) {       /* constexpr bound -> full unroll */    \
    __syncthreads();   /* drains DMA(k): one full compute phase in flight */   \
    if (k + 1 < KT) {                                                          \
      char* d = (char*)&As[(k + 1) & 1][0] + wave * 4096 + lane * 16;          \
      const char* g = gA + (size_t)(k + 1) * 128;                              \
      _Pragma("unroll")                                                        \
      for (int j = 0; j < 4; ++j)                                              \
        GLD_LDS(g + (size_t)j * 8 * rowb, d + j * 1024);                       \
    }                                                                          \
    const char* bA = (const char*)&As[k & 1][0];                               \
    {                                                                          \
      short8 Fb[4], Fa[4];                                                     \
      _Pragma("unroll")                                                        \
      for (int ni = 0; ni < 4; ++ni)                                           \
        Fb[ni] = *(const short8*)(gBk + ni * 1024);                            \
      _Pragma("unroll")                                                        \
      for (int mi = 0; mi < 4; ++mi)                                           \
        Fa[mi] = *(const short8*)(bA + fsA + mi * 2048 + sl0);                 \
      _Pragma("unroll")                                                        \
      for (int mi = 0; mi < 4; ++mi)                                           \
        _Pragma("unroll")                                                      \
        for (int ni = 0; ni < 4; ++ni)                                         \
          acc[mi][ni] = __builtin_amdgcn_mfma_f32_16x16x32_bf16(               \
              Fa[mi], Fb[ni], acc[mi][ni], 0, 0, 0);                           \
    }                                                                          \
    gBk += 4096;                                                               \
    {                                                                          \
      short8 Fb[4], Fa[4];                                                     \
      _Pragma("unroll")                                                        \
      for (int ni = 0; ni < 4; ++ni)                                           \
        Fb[ni] = *(const short8*)(gBk + ni * 1024);                            \
      _Pragma("unroll")                                                        \
      for (int mi = 0; mi < 4; ++mi)                                           \
        Fa[mi] = *(const short8*)(bA + fsA + mi * 2048 + sl1);                 \
      _Pragma("unroll")                                                        \
      for (int mi = 0; mi < 4; ++mi)                                           \
        _Pragma("unroll")                                                      \
        for (int ni = 0; ni < 4; ++ni)                                         \
          acc[mi][ni] = __builtin_amdgcn_mfma_f32_16x16x32_bf16(               \
              Fa[mi], Fb[ni], acc[mi][ni], 0, 0, 0);                           \
    }                                                                          \
    gBk += 4096;                                                               \
  }

#define ACC_INIT                                                               \
  floatx4 acc[4][4];                                                           \
  _Pragma("unroll")                                                            \
  for (int i = 0; i < 4; ++i)                                                  \
    _Pragma("unroll")                                                          \
    for (int j = 0; j < 4; ++j) acc[i][j] = (floatx4){0.f, 0.f, 0.f, 0.f}

// ---------------------------------------------------------------------------
// GEMM: C = relu(A @ B^T + bias), bf16 out (row-major). Bf frag-major.
// ---------------------------------------------------------------------------
template <int K>
__global__ __launch_bounds__(256, 4) void gemm_bias_relu(
    const unsigned short* __restrict__ A,
    const unsigned short* __restrict__ Bf,
    const float* __restrict__ bias,
    unsigned short* __restrict__ C,
    int M, int N) {
  GEMM_CORE_V11(ACC_INIT)

  // Epilogue: C/D layout col=lane&15, row=(lane>>4)*4+reg
#pragma unroll
  for (int ni = 0; ni < 4; ++ni) {
    const int gn = n0 + wn + ni * 16 + fr;
    const float bv = bias[gn];
#pragma unroll
    for (int mi = 0; mi < 4; ++mi) {
#pragma unroll
      for (int r = 0; r < 4; ++r) {
        const int gm = m0 + wm + mi * 16 + fq * 4 + r;
        float v = acc[mi][ni][r] + bv;
        v = v > 0.f ? v : 0.f;
        C[(size_t)gm * N + gn] = f_to_bf_raw(v);
      }
    }
  }
}

// ---------------------------------------------------------------------------
// Fused heads GEMM: relu(G @ WH^T + bias2048) dotted with w2cat in-register,
// non-atomic partials part[j][row], j = blockIdx.y*2 + wave_half in [0,32).
// j 0..7 coverage, 8..15 tracking, 16..31 cooperation.
// ---------------------------------------------------------------------------
template <int K>
__global__ __launch_bounds__(256, 4) void gemm_heads_fused(
    const unsigned short* __restrict__ A,    // G row-major [B,1024]
    const unsigned short* __restrict__ Bf,   // WHf frag-major [2048,1024]
    const float* __restrict__ bias,          // bias2048
    const float* __restrict__ w2,            // w2cat
    float* __restrict__ part,                // [32][B_ROWS]
    int M, int N) {
  GEMM_CORE_V11(ACC_INIT)

  const int j = blockIdx.y * 2 + (wave >> 1);
  float w2v[4], bv[4];
#pragma unroll
  for (int ni = 0; ni < 4; ++ni) {
    const int gn = n0 + wn + ni * 16 + fr;
    w2v[ni] = w2[gn];
    bv[ni]  = bias[gn];
  }
#pragma unroll
  for (int mi = 0; mi < 4; ++mi) {
#pragma unroll
    for (int r = 0; r < 4; ++r) {
      float p = 0.f;
#pragma unroll
      for (int ni = 0; ni < 4; ++ni) {
        float v = acc[mi][ni][r] + bv[ni];
        v = v > 0.f ? v : 0.f;
        p += v * w2v[ni];
      }
      p += __shfl_xor(p, 1);
      p += __shfl_xor(p, 2);
      p += __shfl_xor(p, 4);
      p += __shfl_xor(p, 8);
      if (fr == 0) {
        const int gm = m0 + wm + mi * 16 + fq * 4 + r;
        part[(size_t)j * B_ROWS + gm] = p;
      }
    }
  }
}

// ---------------------------------------------------------------------------
// Final: sum partials, sigmoid, broadcast to out [3, B, 9]. 1 thread/row.
// ---------------------------------------------------------------------------
__global__ __launch_bounds__(256) void final_out(
    const float* __restrict__ part,
    const float* __restrict__ bc2, const float* __restrict__ bt2,
    const float* __restrict__ bk2, float* __restrict__ out) {
  const int row = blockIdx.x * 256 + threadIdx.x;
  float sc = 0.f, st = 0.f, sk = 0.f;
#pragma unroll
  for (int j = 0; j < 8; ++j)  sc += part[(size_t)j * B_ROWS + row];
#pragma unroll
  for (int j = 8; j < 16; ++j) st += part[(size_t)j * B_ROWS + row];
#pragma unroll
  for (int j = 16; j < 32; ++j) sk += part[(size_t)j * B_ROWS + row];
  const float cv = 1.f / (1.f + expf(-(sc + bc2[0])));
  const float tv = 1.f / (1.f + expf(-(st + bt2[0])));
  const float kv = 1.f / (1.f + expf(-(sk + bk2[0])));
  float* o0 = out + (size_t)row * N_AG;
  float* o1 = out + (size_t)(B_ROWS + row) * N_AG;
  float* o2 = out + (size_t)(2 * B_ROWS + row) * N_AG;
#pragma unroll
  for (int a = 0; a < N_AG; ++a) { o0[a] = cv; o1[a] = tv; o2[a] = kv; }
}

// ---------------------------------------------------------------------------
extern "C" void kernel_launch(void* const* d_in, const int* in_sizes, int n_in,
                              void* d_out, int out_size, void* d_ws, size_t ws_size,
                              hipStream_t stream) {
  const float* obs = (const float*)d_in[0];
  // d_in[1] agent_positions: unused (outputs don't depend on it)
  const float* W1  = (const float*)d_in[2];
  const float* b1  = (const float*)d_in[3];
  const float* W2  = (const float*)d_in[4];
  const float* b2  = (const float*)d_in[5];
  const float* Wc1 = (const float*)d_in[6];
  const float* bc1 = (const float*)d_in[7];
  const float* Wc2 = (const float*)d_in[8];
  const float* bc2 = (const float*)d_in[9];
  const float* Wt1 = (const float*)d_in[10];
  const float* bt1 = (const float*)d_in[11];
  const float* Wt2 = (const float*)d_in[12];
  const float* bt2 = (const float*)d_in[13];
  const float* Wk1 = (const float*)d_in[14];
  const float* bk1 = (const float*)d_in[15];
  const float* Wk2 = (const float*)d_in[16];
  const float* bk2 = (const float*)d_in[17];
  float* out = (float*)d_out;

  // Workspace layout. PART aliases obs_bf (disjoint lifetimes).
  char* ws = (char*)d_ws;
  unsigned short* obs_bf  = (unsigned short*)(ws + 0);         // 16 MB
  float*          PART    = (float*)(ws + 0);                  // 2 MB (alias)
  unsigned short* W1f     = (unsigned short*)(ws + 16777216);  // 1 MB  frag-major
  unsigned short* W2f     = (unsigned short*)(ws + 17825792);  // 2 MB  frag-major
  unsigned short* WHf     = (unsigned short*)(ws + 19922944);  // 4 MB  frag-major
  float*          bias2048= (float*)(ws + 24117248);           // 8 KB
  float*          w2cat   = (float*)(ws + 24125440);           // 8 KB
  unsigned short* G1      = (unsigned short*)(ws + 24330240);  // 32 MB
  unsigned short* G       = (unsigned short*)(ws + 57884672);  // 32 MB

  prep_all<<<7688, 256, 0, stream>>>(obs, W1, W2, Wc1, Wt1, Wk1,
                                     bc1, bt1, bk1, Wc2, Wt2, Wk2,
                                     obs_bf, W1f, W2f, WHf, bias2048, w2cat);

  gemm_bias_relu<512><<<dim3(128, 8), 256, 0, stream>>>(obs_bf, W1f, b1, G1, B_ROWS, 1024);
  gemm_bias_relu<1024><<<dim3(128, 8), 256, 0, stream>>>(G1, W2f, b2, G, B_ROWS, 1024);

  gemm_heads_fused<1024><<<dim3(128, 16), 256, 0, stream>>>(G, WHf, bias2048, w2cat, PART,
                                                            B_ROWS, 2048);

  final_out<<<B_ROWS / 256, 256, 0, stream>>>(PART, bc2, bt2, bk2, out);
}